// Round 13
// baseline (372.909 us; speedup 1.0000x reference)
//
#include <hip/hip_runtime.h>
#include <hip/hip_bf16.h>
#include <math.h>

typedef unsigned short u16;
typedef short bf16x8 __attribute__((ext_vector_type(8)));
typedef float f32x4 __attribute__((ext_vector_type(4)));

#define EMB   1024
#define HEADS 16
#define HD    64
#define LATD  256
#define FFND  4096
#define BATCH 2
#define SEQ   2048
#define TOK   (BATCH*SEQ)   // 4096

#define SCL2  0.18033688011112042f    // 0.125 * log2(e)  (folded into Wq/bq)
#define LOG2E 1.4426950408889634f

__device__ __forceinline__ float bf2f(u16 u) {
    union { unsigned int i; float f; } x; x.i = ((unsigned int)u) << 16; return x.f;
}
__device__ __forceinline__ float bfLO(unsigned int u) {
    union { unsigned int i; float f; } x; x.i = u << 16; return x.f;
}
__device__ __forceinline__ float bfHI(unsigned int u) {
    union { unsigned int i; float f; } x; x.i = u & 0xffff0000u; return x.f;
}
__device__ __forceinline__ u16 f2bf(float f) {
    union { float f; unsigned int i; } x; x.f = f;
    unsigned int i = x.i;
    unsigned int lsb = (i >> 16) & 1u;
    i += 0x7fffu + lsb;       // round-to-nearest-even
    return (u16)(i >> 16);
}
__device__ __forceinline__ void gld16(const u16* g, u16* l) {
    __builtin_amdgcn_global_load_lds(
        (const __attribute__((address_space(1))) void*)g,
        (__attribute__((address_space(3))) void*)l, 16, 0, 0);
}
__device__ __forceinline__ unsigned int cvt_pk_bf16(float a, float b) {
    unsigned int r;
    asm("v_cvt_pk_bf16_f32 %0, %1, %2" : "=v"(r) : "v"(a), "v"(b));
    return r;   // lo = bf16(a), hi = bf16(b), RNE
}
#if defined(__has_builtin)
#if __has_builtin(__builtin_amdgcn_exp2f)
#define EXP2(x) __builtin_amdgcn_exp2f(x)
#endif
#endif
#ifndef EXP2
#define EXP2(x) exp2f(x)
#endif

// ---------------------------------------------------------------- merged transpose descriptor
struct TDesc { const float* src; u16* dst; int K; int N; int ofs; float scl; };
struct TTable { TDesc d[8]; };

// ---------------------------------------------------------------- merged prep kernel:
// [0,2048)      : fp32->bf16 cvt of x
// [2048,2054)   : bias prep (concat baK|baV, bq*SCL2)
// [2054,2566)   : permute attn_bias -> abP (S^T C-frag order, x log2e, BF16 packed)
// [2566,13830)  : 8 weight transposes (fp32 -> bf16^T, optional scale)
struct PrepArgs {
    const float* x; u16* xb;
    const float* baK; const float* baV; const float* bq; float* bKV; float* bqs;
    const float* ab; u16* abP;
    TTable tt;
};

__global__ __launch_bounds__(256) void prep_all_kernel(PrepArgs pa)
{
    __shared__ u16 t[32][33];
    int blk = blockIdx.x;
    const int tid = threadIdx.x;

    if (blk < 2048) {                       // ---- cvt x -> xb (bf16), 8 elems/thread
        int i = blk * 256 + tid;            // covers TOK*EMB/8 exactly
        float4 f0 = *(const float4*)(pa.x + (size_t)i * 8);
        float4 f1 = *(const float4*)(pa.x + (size_t)i * 8 + 4);
        u16 e[8];
        e[0] = f2bf(f0.x); e[1] = f2bf(f0.y); e[2] = f2bf(f0.z); e[3] = f2bf(f0.w);
        e[4] = f2bf(f1.x); e[5] = f2bf(f1.y); e[6] = f2bf(f1.z); e[7] = f2bf(f1.w);
        *(uint4*)(pa.xb + (size_t)i * 8) = *(const uint4*)e;
        return;
    }
    blk -= 2048;
    if (blk < 6) {                          // ---- bias prep
        int i = blk * 256 + tid;            // 0..1535
        if (i < 256)      pa.bKV[i] = pa.baK[i];
        else if (i < 512) pa.bKV[i] = pa.baV[i - 256];
        else              pa.bqs[i - 512] = pa.bq[i - 512] * SCL2;
        return;
    }
    blk -= 6;
    if (blk < 512) {                        // ---- permute attn_bias (bf16 packed out)
        const int kt = blk & 31, qt = blk >> 5;
        const int lane = tid & 63, wq = tid >> 6;
        const int qq = lane >> 4, col = lane & 15;
#pragma unroll
        for (int wi = wq; wi < 8; wi += 4)
#pragma unroll
            for (int mt = 0; mt < 4; mt++) {
                float4 v = *(const float4*)(pa.ab + (size_t)(qt * 128 + wi * 16 + col) * SEQ
                                            + kt * 64 + mt * 16 + qq * 4);
                uint2 pk;
                pk.x = cvt_pk_bf16(v.x * LOG2E, v.y * LOG2E);
                pk.y = cvt_pk_bf16(v.z * LOG2E, v.w * LOG2E);
                *(uint2*)(pa.abP + (((size_t)qt * 32 + kt) * 8 + wi) * 1024 + mt * 256 + lane * 4) = pk;
            }
        return;
    }
    blk -= 512;
    {                                       // ---- weight transposes
        int tb = blk, e = 0;
#pragma unroll
        for (int i = 1; i < 8; i++) if (tb >= pa.tt.d[i].ofs) e = i;
        const float* src = pa.tt.d[e].src;
        u16* dst = pa.tt.d[e].dst;
        const int K = pa.tt.d[e].K, N = pa.tt.d[e].N;
        const float scl = pa.tt.d[e].scl;
        const int local = tb - pa.tt.d[e].ofs;
        const int nx = N >> 5;
        const int bx = (local % nx) * 32;
        const int by = (local / nx) * 32;
        const int tx = tid & 31;
        const int ty = tid >> 5;
#pragma unroll
        for (int i = 0; i < 32; i += 8)
            t[ty + i][tx] = f2bf(src[(size_t)(by + ty + i) * N + bx + tx] * scl);
        __syncthreads();
#pragma unroll
        for (int i = 0; i < 32; i += 8)
            dst[(size_t)(bx + ty + i) * K + by + tx] = t[tx][ty + i];
    }
}

// ---------------------------------------------------------------- XCD-aware block swizzle (requires nwg % 8 == 0)
__device__ __forceinline__ void xcd_swz(int& bx, int& by)
{
    const int gx = gridDim.x;
    const int nwg = gx * gridDim.y;
    const int flat = blockIdx.x + gx * blockIdx.y;
    const int swz = (flat & 7) * (nwg >> 3) + (flat >> 3);
    bx = swz % gx;
    by = swz / gx;
}

// ---------------------------------------------------------------- MFMA GEMM body (B^T, async staging, BK=64, xor-swizzled LDS)
// TRC=1 (requires BNv=64, N=1024, M spanning TOK): store C transposed as
// C[b][n][tok] (n = bx*64 + n_local, tok = m % SEQ) via LDS round-trip.
#define BM 128
#define GBK 64

template <int ACT, int BNv, int TRC>
__device__ __forceinline__ void gemm_body(
    const u16* __restrict__ A, int lda, const u16* __restrict__ WT,
    const float* __restrict__ bias, u16* __restrict__ C,
    int K, int N, int bx, int by, u16* Al, u16* Wl, u16* Tl)
{
    const int NT = BNv / 32;
    const int WN = BNv / 2;
    const int CW = BNv / 32;      // W 16B-chunks per lane (BNv*8 / 256)

    const int tid  = threadIdx.x;
    const int lane = tid & 63;
    const int w    = tid >> 6;
    const int wm = w >> 1, wn = w & 1;
    const int col = lane & 15, qq = lane >> 4;
    const size_t bm = (size_t)by * BM;
    const size_t bn = (size_t)bx * BNv;

    f32x4 acc[4][NT];
#pragma unroll
    for (int mt = 0; mt < 4; mt++)
#pragma unroll
        for (int nt = 0; nt < NT; nt++) acc[mt][nt] = (f32x4){0.f, 0.f, 0.f, 0.f};

    const u16* gA[4]; u16* lA[4];
#pragma unroll
    for (int i = 0; i < 4; i++) {
        int f = w * 256 + i * 64 + lane;
        int r = f >> 3, s = f & 7, sg = s ^ (r & 7);
        gA[i] = A + (bm + r) * (size_t)lda + sg * 8;
        lA[i] = &Al[(size_t)(w * 256 + i * 64) * 8];
    }
    const u16* gW[4]; u16* lW[4];
#pragma unroll
    for (int i = 0; i < CW; i++) {
        int f = w * (BNv * 2) + i * 64 + lane;
        int r = f >> 3, s = f & 7, sg = s ^ (r & 7);
        gW[i] = WT + (bn + r) * (size_t)K + sg * 8;
        lW[i] = &Wl[(size_t)(w * (BNv * 2) + i * 64) * 8];
    }

    for (int k0 = 0; k0 < K; k0 += GBK) {
#pragma unroll
        for (int i = 0; i < 4; i++) gld16(gA[i] + k0, lA[i]);
#pragma unroll
        for (int i = 0; i < CW; i++) gld16(gW[i] + k0, lW[i]);
        __syncthreads();

#pragma unroll
        for (int kk = 0; kk < 2; kk++) {
            bf16x8 af[4], bfr[NT];
#pragma unroll
            for (int mt = 0; mt < 4; mt++) {
                int rr = wm * 64 + mt * 16 + col;
                int sub = (kk * 4 + qq) ^ (rr & 7);
                af[mt] = *(const bf16x8*)&Al[rr * GBK + sub * 8];
            }
#pragma unroll
            for (int nt = 0; nt < NT; nt++) {
                int rn = wn * WN + nt * 16 + col;
                int sub = (kk * 4 + qq) ^ (rn & 7);
                bfr[nt] = *(const bf16x8*)&Wl[rn * GBK + sub * 8];
            }
#pragma unroll
            for (int mt = 0; mt < 4; mt++)
#pragma unroll
                for (int nt = 0; nt < NT; nt++)
                    acc[mt][nt] = __builtin_amdgcn_mfma_f32_16x16x32_bf16(
                        af[mt], bfr[nt], acc[mt][nt], 0, 0, 0);
        }
        __syncthreads();
    }

    float bv[NT];
#pragma unroll
    for (int nt = 0; nt < NT; nt++)
        bv[nt] = bias[bn + wn * WN + nt * 16 + col];

    if (TRC) {
        // transposed store: Tl[n_local][m_local], pitch 136
#pragma unroll
        for (int mt = 0; mt < 4; mt++)
#pragma unroll
            for (int nt = 0; nt < NT; nt++)
#pragma unroll
                for (int r = 0; r < 4; r++) {
                    float v = acc[mt][nt][r] + bv[nt];
                    Tl[(wn * WN + nt * 16 + col) * 136 + (wm * 64 + mt * 16 + qq * 4 + r)] = f2bf(v);
                }
        __syncthreads();
        const int b_ = (int)(bm >> 11);            // bm / SEQ (BM=128 divides SEQ)
        const size_t tokb = bm & (SEQ - 1);
        const int row = tid >> 2;                  // 0..63 (n_local)
        u16* dst = C + ((size_t)b_ * EMB + (size_t)bx * 64 + row) * SEQ + tokb;
        const u16* srcl = Tl + row * 136;
#pragma unroll
        for (int j = 0; j < 4; j++) {
            int c0 = ((tid & 3) + j * 4) * 8;
            *(uint4*)(dst + c0) = *(const uint4*)(srcl + c0);
        }
        return;
    }

#pragma unroll
    for (int mt = 0; mt < 4; mt++) {
#pragma unroll
        for (int nt = 0; nt < NT; nt++) {
#pragma unroll
            for (int r = 0; r < 4; r++) {
                float v = acc[mt][nt][r] + bv[nt];
                if (ACT == 1) v = 0.5f * v * (1.0f + erff(v * 0.70710678118654752f));
                size_t rg = bm + wm * 64 + mt * 16 + qq * 4 + r;
                C[rg * (size_t)N + bn + wn * WN + nt * 16 + col] = f2bf(v);
            }
        }
    }
}

// plain single-segment GEMM
template <int ACT, int BNv, int MINW>
__global__ __launch_bounds__(256, MINW) void gemm_bt_kernel(
    const u16* __restrict__ A, int lda, const u16* __restrict__ WT,
    const float* __restrict__ bias, u16* __restrict__ C,
    int K, int N)
{
    __shared__ __align__(16) u16 Al[BM * GBK];
    __shared__ __align__(16) u16 Wl[BNv * GBK];
    int bx, by;
    xcd_swz(bx, by);
    gemm_body<ACT, BNv, 0>(A, lda, WT, bias, C, K, N, bx, by, Al, Wl, Al);
}

// two-segment merged GEMM (same K both segments); TRV -> segment 1 stores C^T
struct GPair {
    const u16* A0; const u16* A1;
    const u16* W0; const u16* W1;
    const float* b0; const float* b1;
    u16* C0; u16* C1;
    int lda0, lda1, N0, N1, nx0;
};

template <int BNv, int MINW, int TRV>
__global__ __launch_bounds__(256, MINW) void gemm_pair_kernel(GPair p, int K)
{
    __shared__ __align__(16) u16 SH[BM * GBK + BNv * GBK];
    u16* Al = SH;
    u16* Wl = SH + BM * GBK;
    int bxs, by;
    xcd_swz(bxs, by);
    const bool s1 = bxs >= p.nx0;
    const u16* A = s1 ? p.A1 : p.A0;
    const u16* WT = s1 ? p.W1 : p.W0;
    const float* bias = s1 ? p.b1 : p.b0;
    u16* C = s1 ? p.C1 : p.C0;
    const int lda = s1 ? p.lda1 : p.lda0;
    const int N = s1 ? p.N1 : p.N0;
    const int bx = s1 ? bxs - p.nx0 : bxs;
    if (TRV && s1)
        gemm_body<0, BNv, 1>(A, lda, WT, bias, C, K, N, bx, by, Al, Wl, SH);
    else
        gemm_body<0, BNv, 0>(A, lda, WT, bias, C, K, N, bx, by, Al, Wl, SH);
}

// ---------------------------------------------------------------- flash attention (MFMA), swapped-QK^T + swapped-PV
// SPLIT=0: grid (16, 32); full KV range; writes normalized bf16 O.
// SPLIT=1: grid (16, 32, 2); blockIdx.z selects KV half (16 tiles); writes
//   unnormalized f32 partial O to Of[z] and per-q-row (m,l) to Ml[z] — combined
//   by reduce_o_kernel. Doubles block count (2->3 blocks/CU) for latency hiding.
// K/V LDS: LDK=64 + XOR-swizzle (chunk c -> c^(row&7)) => conflict-free b128 reads.
#define BQ   128
#define BKV  64
#define NKVT (SEQ / BKV)   // 32
#define LDP  72

template <int SPLIT>
__global__ __launch_bounds__(512, 4) void fattn_kernel(
    const u16* __restrict__ Q, const u16* __restrict__ K,
    const u16* __restrict__ VT, const u16* __restrict__ abP,
    u16* __restrict__ O, float* __restrict__ Of0, float* __restrict__ Of1,
    float* __restrict__ Ml)
{
    __shared__ __align__(16) u16 Ks[2][BKV * 64];    // 2 x 8,192 B
    __shared__ __align__(16) u16 Vt[2][HD * 64];     // 2 x 8,192 B
    __shared__ __align__(16) u16 Ps[BQ * LDP];       //    18,432 B  -> total 51,200 B

    const int tid = threadIdx.x;
    const int lane = tid & 63;
    const int w = tid >> 6;                       // 0..7
    const int col = lane & 15, qq = lane >> 4;
    const int qt = blockIdx.x;                    // 0..15
    const int b = blockIdx.y >> 4, h = blockIdx.y & 15;
    const int zh = SPLIT ? (int)blockIdx.z : 0;   // KV half
    const int t0 = zh << 4;                       // first tile index
    const int NTL = SPLIT ? 16 : 32;              // tiles this block
    const size_t tok0 = (size_t)b * SEQ + (size_t)qt * BQ;
    const int wrow = w * 16;
    const size_t kvbase = (size_t)b * SEQ * EMB + h * HD;
    const size_t vtb = ((size_t)b * EMB + h * HD) * SEQ;

    // staging indices (512 threads): 64 rows x 8 chunks of 8 elems, 1 uint4/thr each of K,V
    const int krow = tid >> 3;                    // 0..63
    const int kch  = tid & 7;                     // chunk
    const int kcol = kch * 8;                     // global k offset (linear)
    const int ksw  = (kch ^ (krow & 7)) * 8;      // swizzled LDS chunk offset

    // Q fragment: B-operand of S^T (n = q = col, k = kk*32 + qq*8); Q is pre-scaled
    bf16x8 aq[2];
#pragma unroll
    for (int kk = 0; kk < 2; kk++)
        aq[kk] = *(const bf16x8*)(Q + (tok0 + wrow + col) * EMB + h * HD + kk * 32 + qq * 8);

    float m_st = -1e30f, l_st = 0.f;
    f32x4 o_acc[4];
#pragma unroll
    for (int dt = 0; dt < 4; dt++) o_acc[dt] = (f32x4){0.f, 0.f, 0.f, 0.f};

    // swizzled read chunk offsets (row = *16+col => row&7 == col&7)
    const int c7 = col & 7;
    const int sw0 = (qq ^ c7) * 8;                // kk=0 chunk
    const int sw1 = ((4 + qq) ^ c7) * 8;          // kk=1 chunk

    uint4 kreg, vreg;
#define LOADKV(KV0) do {                                                              \
        kreg = *(const uint4*)(K + kvbase + (size_t)((KV0) + krow) * EMB + kcol);     \
        vreg = *(const uint4*)(VT + vtb + (size_t)krow * SEQ + (KV0) + kcol);         \
    } while (0)

    // prologue: stage first tile into buffer 0 (swizzled), then issue loads for next
    LOADKV(t0 * BKV);
    *(uint4*)&Ks[0][krow * 64 + ksw] = kreg;
    *(uint4*)&Vt[0][krow * 64 + ksw] = vreg;
    __syncthreads();
    LOADKV((t0 + 1) * BKV);

    // attn-bias fragments for first tile (bf16 packed; prefetched each iteration)
    const u16* abq = abP + ((size_t)qt * NKVT + t0) * 8192 + (size_t)w * 1024;
    uint2 abr[4];
#pragma unroll
    for (int mt = 0; mt < 4; mt++)
        abr[mt] = *(const uint2*)(abq + mt * 256 + lane * 4);

    for (int t = 0; t < NTL; t++) {
        const int cur = t & 1;
        const u16* Kc = Ks[cur];

        // S^T = K·Q^T + bias (unpack bf16 bias to f32 acc; already log2-domain)
        f32x4 s2[4];
#pragma unroll
        for (int mt = 0; mt < 4; mt++) {
            s2[mt][0] = bfLO(abr[mt].x);
            s2[mt][1] = bfHI(abr[mt].x);
            s2[mt][2] = bfLO(abr[mt].y);
            s2[mt][3] = bfHI(abr[mt].y);
        }
        __builtin_amdgcn_s_setprio(1);
#pragma unroll
        for (int mt = 0; mt < 4; mt++) {
            bf16x8 ak0 = *(const bf16x8*)&Kc[(mt * 16 + col) * 64 + sw0];
            bf16x8 ak1 = *(const bf16x8*)&Kc[(mt * 16 + col) * 64 + sw1];
            s2[mt] = __builtin_amdgcn_mfma_f32_16x16x32_bf16(ak0, aq[0], s2[mt], 0, 0, 0);
            s2[mt] = __builtin_amdgcn_mfma_f32_16x16x32_bf16(ak1, aq[1], s2[mt], 0, 0, 0);
        }
        __builtin_amdgcn_s_setprio(0);

        // prefetch next tile's bias into regs
        if (t + 1 < NTL) {
            const u16* abn = abq + (size_t)(t + 1) * 8192;
#pragma unroll
            for (int mt = 0; mt < 4; mt++)
                abr[mt] = *(const uint2*)(abn + mt * 256 + lane * 4);
        }

        // stage next tile into the other buffer (swizzled; overlaps with this tile's compute)
        if (t + 1 < NTL) {
            *(uint4*)&Ks[cur ^ 1][krow * 64 + ksw] = kreg;
            *(uint4*)&Vt[cur ^ 1][krow * 64 + ksw] = vreg;
        }
        if (t + 2 < NTL) LOADKV((t0 + t + 2) * BKV);

        // online softmax (log2 domain), defer-max with THR=8
        float t0_ = fmaxf(fmaxf(s2[0][0], s2[0][1]), fmaxf(s2[0][2], s2[0][3]));
        float t1_ = fmaxf(fmaxf(s2[1][0], s2[1][1]), fmaxf(s2[1][2], s2[1][3]));
        float t2_ = fmaxf(fmaxf(s2[2][0], s2[2][1]), fmaxf(s2[2][2], s2[2][3]));
        float t3_ = fmaxf(fmaxf(s2[3][0], s2[3][1]), fmaxf(s2[3][2], s2[3][3]));
        float tm = fmaxf(fmaxf(t0_, t1_), fmaxf(t2_, t3_));
        tm = fmaxf(tm, __shfl_xor(tm, 16));
        tm = fmaxf(tm, __shfl_xor(tm, 32));
        if (!__all(tm <= m_st + 8.f)) {
            float mnew = fmaxf(m_st, tm);
            float alpha = EXP2(m_st - mnew);
            m_st = mnew;
            l_st *= alpha;
#pragma unroll
            for (int dt = 0; dt < 4; dt++)
#pragma unroll
                for (int r = 0; r < 4; r++) o_acc[dt][r] *= alpha;   // per-lane (col-uniform)
        }
        float rs = 0.f;
#pragma unroll
        for (int mt = 0; mt < 4; mt++)
#pragma unroll
            for (int r = 0; r < 4; r++) {
                float e = EXP2(s2[mt][r] - m_st);
                s2[mt][r] = e;
                rs += e;
            }
        rs += __shfl_xor(rs, 16);
        rs += __shfl_xor(rs, 32);
        l_st += rs;

        // P pack -> LDS: row q = wrow+col (wave-private), kv = mt*16 + qq*4..+3
#pragma unroll
        for (int mt = 0; mt < 4; mt++) {
            uint2 pp;
            pp.x = cvt_pk_bf16(s2[mt][0], s2[mt][1]);
            pp.y = cvt_pk_bf16(s2[mt][2], s2[mt][3]);
            *(uint2*)&Ps[(wrow + col) * LDP + mt * 16 + qq * 4] = pp;
        }

        // O^T += V^T @ P^T (swapped operands; same-wave LDS RAW is in-order)
        __builtin_amdgcn_s_setprio(1);
#pragma unroll
        for (int kk = 0; kk < 2; kk++) {
            bf16x8 ap = *(const bf16x8*)&Ps[(wrow + col) * LDP + kk * 32 + qq * 8];
            const int swv = ((kk * 4 + qq) ^ c7) * 8;
#pragma unroll
            for (int dt = 0; dt < 4; dt++) {
                bf16x8 bv = *(const bf16x8*)&Vt[cur][(dt * 16 + col) * 64 + swv];
                o_acc[dt] = __builtin_amdgcn_mfma_f32_16x16x32_bf16(bv, ap, o_acc[dt], 0, 0, 0);
            }
        }
        __builtin_amdgcn_s_setprio(0);
        __syncthreads();
    }
#undef LOADKV

    const size_t tokg = tok0 + wrow + col;        // per-lane q row
    if (SPLIT) {
        // partial epilogue: unnormalized f32 O + (m,l) per q-row
        float* Ofh = zh ? Of1 : Of0;
#pragma unroll
        for (int dt = 0; dt < 4; dt++)
            *(f32x4*)(Ofh + tokg * EMB + h * HD + dt * 16 + qq * 4) = o_acc[dt];
        if (qq == 0)
            ((float2*)Ml)[(size_t)zh * TOK * HEADS + tokg * HEADS + h] =
                make_float2(m_st, l_st);
    } else {
        // normalized bf16 epilogue: d = dt*16 + qq*4 + r -> packed 8B stores
        float lr = 1.0f / l_st;
#pragma unroll
        for (int dt = 0; dt < 4; dt++) {
            uint2 pp;
            pp.x = cvt_pk_bf16(o_acc[dt][0] * lr, o_acc[dt][1] * lr);
            pp.y = cvt_pk_bf16(o_acc[dt][2] * lr, o_acc[dt][3] * lr);
            *(uint2*)(O + tokg * EMB + h * HD + dt * 16 + qq * 4) = pp;
        }
    }
}

// ---------------------------------------------------------------- combine KV-split partials
// O[tok][h*64+d] = (Of0*2^(m0-m) + Of1*2^(m1-m)) / (l0*2^(m0-m) + l1*2^(m1-m))
// grid 4096 x 256 thr; 16 threads per (tok,h), 4 d each.
__global__ __launch_bounds__(256) void reduce_o_kernel(
    const float* __restrict__ Of0, const float* __restrict__ Of1,
    const float* __restrict__ Ml, u16* __restrict__ O)
{
    const int idx = blockIdx.x * 256 + threadIdx.x;   // < TOK*HEADS*16
    const int th = idx >> 4;                          // tok*16 + h
    const int dg = (idx & 15) * 4;
    const int tok = th >> 4, h = th & 15;

    const float2* Ml2 = (const float2*)Ml;
    float2 a = Ml2[th];
    float2 c = Ml2[TOK * HEADS + th];
    float m = fmaxf(a.x, c.x);
    float w1 = EXP2(a.x - m), w2 = EXP2(c.x - m);
    float inv = 1.0f / (a.y * w1 + c.y * w2);

    const size_t base = (size_t)tok * EMB + h * HD + dg;
    f32x4 o1 = *(const f32x4*)(Of0 + base);
    f32x4 o2 = *(const f32x4*)(Of1 + base);
    uint2 pp;
    pp.x = cvt_pk_bf16((o1[0] * w1 + o2[0] * w2) * inv, (o1[1] * w1 + o2[1] * w2) * inv);
    pp.y = cvt_pk_bf16((o1[2] * w1 + o2[2] * w2) * inv, (o1[3] * w1 + o2[3] * w2) * inv);
    *(uint2*)(O + base) = pp;
}

// ---------------------------------------------------------------- residual + LayerNorm (vectorized: 4 consecutive cols/thread)
template <int AF32, int OUTF32>
__global__ __launch_bounds__(256) void ln_kernel(
    const void* __restrict__ A, const u16* __restrict__ R,
    const float* __restrict__ w, const float* __restrict__ bb,
    void* __restrict__ out)
{
    __shared__ float r1[4], r2[4];
    const int tid = threadIdx.x;
    const size_t row = blockIdx.x;
    const int c0 = tid * 4;

    float v[4];
    {
        float a[4];
        if (AF32) {
            float4 av = *(const float4*)((const float*)A + row * EMB + c0);
            a[0] = av.x; a[1] = av.y; a[2] = av.z; a[3] = av.w;
        } else {
            ushort4 av = *(const ushort4*)((const u16*)A + row * EMB + c0);
            a[0] = bf2f(av.x); a[1] = bf2f(av.y); a[2] = bf2f(av.z); a[3] = bf2f(av.w);
        }
        ushort4 rv = *(const ushort4*)(R + row * EMB + c0);
        v[0] = a[0] + bf2f(rv.x); v[1] = a[1] + bf2f(rv.y);
        v[2] = a[2] + bf2f(rv.z); v[3] = a[3] + bf2f(rv.w);
    }
    float s = (v[0] + v[1]) + (v[2] + v[3]);
    float s2 = (v[0] * v[0] + v[1] * v[1]) + (v[2] * v[2] + v[3] * v[3]);

#pragma unroll
    for (int o = 32; o > 0; o >>= 1) {
        s  += __shfl_down(s, o);
        s2 += __shfl_down(s2, o);
    }
    if ((tid & 63) == 0) { r1[tid >> 6] = s; r2[tid >> 6] = s2; }
    __syncthreads();
    s  = r1[0] + r1[1] + r1[2] + r1[3];
    s2 = r2[0] + r2[1] + r2[2] + r2[3];

    float mu = s * (1.0f / EMB);
    float var = s2 * (1.0f / EMB) - mu * mu;
    float rs = rsqrtf(var + 1e-5f);

    float4 wv = *(const float4*)(w + c0);
    float4 bv = *(const float4*)(bb + c0);
    float y0 = (v[0] - mu) * rs * wv.x + bv.x;
    float y1 = (v[1] - mu) * rs * wv.y + bv.y;
    float y2 = (v[2] - mu) * rs * wv.z + bv.z;
    float y3 = (v[3] - mu) * rs * wv.w + bv.w;
    if (OUTF32) {
        *(float4*)((float*)out + row * EMB + c0) = make_float4(y0, y1, y2, y3);
    } else {
        ushort4 ov;
        ov.x = f2bf(y0); ov.y = f2bf(y1); ov.z = f2bf(y2); ov.w = f2bf(y3);
        *(ushort4*)((u16*)out + row * EMB + c0) = ov;
    }
}

// ---------------------------------------------------------------- launch
extern "C" void kernel_launch(void* const* d_in, const int* in_sizes, int n_in,
                              void* d_out, int out_size, void* d_ws, size_t ws_size,
                              hipStream_t stream)
{
    const float* x    = (const float*)d_in[0];
    const float* ab   = (const float*)d_in[1];
    const float* Wq   = (const float*)d_in[2];
    const float* bq   = (const float*)d_in[3];
    const float* WaK  = (const float*)d_in[4];
    const float* baK  = (const float*)d_in[5];
    const float* WbK  = (const float*)d_in[6];
    const float* bbK  = (const float*)d_in[7];
    const float* WaV  = (const float*)d_in[8];
    const float* baV  = (const float*)d_in[9];
    const float* WbV  = (const float*)d_in[10];
    const float* bbV  = (const float*)d_in[11];
    const float* Wo   = (const float*)d_in[12];
    const float* bo   = (const float*)d_in[13];
    const float* W1   = (const float*)d_in[14];
    const float* b1   = (const float*)d_in[15];
    const float* W2   = (const float*)d_in[16];
    const float* b2   = (const float*)d_in[17];
    const float* ln1w = (const float*)d_in[18];
    const float* ln1b = (const float*)d_in[19];
    const float* ln2w = (const float*)d_in[20];
    const float* ln2b = (const float*)d_in[21];

    u16* w = (u16*)d_ws;
    size_t o = 0;
    u16* WqT  = w + o; o += (size_t)EMB * EMB;
    u16* WaKT = w + o; o += (size_t)EMB * LATD;    // WaKT+WaVT contiguous = combined WT
    u16* WaVT = w + o; o += (size_t)EMB * LATD;
    u16* WbKT = w + o; o += (size_t)LATD * EMB;
    u16* WbVT = w + o; o += (size_t)LATD * EMB;
    u16* WoT  = w + o; o += (size_t)EMB * EMB;
    u16* W1T  = w + o; o += (size_t)EMB * FFND;
    u16* W2T  = w + o; o += (size_t)FFND * EMB;
    u16* Qb   = w + o; o += (size_t)TOK * EMB;
    u16* Kb   = w + o; o += (size_t)TOK * EMB;
    u16* Vb   = w + o; o += (size_t)TOK * EMB;     // holds VbT: [b][h*64+d][tok]
    u16* aOb  = w + o; o += (size_t)TOK * EMB;
    u16* projb= w + o; o += (size_t)TOK * EMB;
    u16* hb   = w + o; o += (size_t)TOK * EMB;
    u16* xb   = w + o; o += (size_t)TOK * EMB;     // bf16 x (own slot)
    float* bKV = (float*)(w + o); o += 1024;       // 512 fp32 concat bias
    float* bqs = (float*)(w + o); o += 2048;       // 1024 fp32 scaled bq
    // overlays (non-overlapping lifetimes):
    u16* abP = projb;                         // 8.4 MB bf16 = projb slot exactly; dead after fattn
    u16* KVa = aOb;                           // [TOK][512]; dead before fattn writes aOb
    u16* f1  = Qb;                            // spans Qb..aOb = TOK*FFND
    u16* f2  = projb;                         // abP/proj dead after ln1

    // KV-split partials (used only if workspace has slack):
    //   Of0 overlays hb+xb (16 MB f32, both dead during fattn);
    //   Of1 (16 MB) + Ml (1 MB) beyond current end.
    float* Of0 = (float*)hb;
    float* Of1 = (float*)(w + o);
    float* Ml  = Of1 + (size_t)TOK * EMB;
    const size_t need_bytes = o * 2 + ((size_t)TOK * EMB + (size_t)2 * TOK * HEADS * 2) * 4;
    const bool split = ws_size >= need_bytes;

    dim3 blk(256);

    // merged prep: cvt | bias | permute_ab(bf16) | 8 transposes (2048+6+512+11264 = 13830 blocks)
    PrepArgs pa;
    pa.x = x; pa.xb = xb;
    pa.baK = baK; pa.baV = baV; pa.bq = bq; pa.bKV = bKV; pa.bqs = bqs;
    pa.ab = ab; pa.abP = abP;
    pa.tt.d[0] = {Wq,  WqT,  EMB,  EMB,  0,    SCL2};   // Q pre-scaled by 0.125*log2e
    pa.tt.d[1] = {WaK, WaKT, EMB,  LATD, 1024, 1.0f};
    pa.tt.d[2] = {WaV, WaVT, EMB,  LATD, 1280, 1.0f};
    pa.tt.d[3] = {WbK, WbKT, LATD, EMB,  1536, 1.0f};
    pa.tt.d[4] = {WbV, WbVT, LATD, EMB,  1792, 1.0f};
    pa.tt.d[5] = {Wo,  WoT,  EMB,  EMB,  2048, 1.0f};
    pa.tt.d[6] = {W1,  W1T,  EMB,  FFND, 3072, 1.0f};
    pa.tt.d[7] = {W2,  W2T,  FFND, EMB,  7168, 1.0f};
    prep_all_kernel<<<dim3(13830), blk, 0, stream>>>(pa);

    // merged: Q = x@(Wq*s)+bq*s (16 n-blocks) | KVa = x@[WaK|WaV]+bKV (8 n-blocks); K=1024
    {
        GPair p;
        p.A0 = xb;  p.A1 = xb;
        p.W0 = WqT; p.W1 = WaKT;
        p.b0 = bqs; p.b1 = bKV;
        p.C0 = Qb;  p.C1 = KVa;
        p.lda0 = EMB; p.lda1 = EMB;
        p.N0 = EMB; p.N1 = 512; p.nx0 = 16;
        gemm_pair_kernel<64, 3, 0><<<dim3(24, TOK / BM), blk, 0, stream>>>(p, EMB);
    }
    // merged: K = Ka@WbK+bbK | V^T = (Va@WbV+bbV)^T; K=256, both N=1024 (16+16 n-blocks)
    {
        GPair p;
        p.A0 = KVa;  p.A1 = KVa + LATD;
        p.W0 = WbKT; p.W1 = WbVT;
        p.b0 = bbK;  p.b1 = bbV;
        p.C0 = Kb;   p.C1 = Vb;          // Vb stored transposed (VbT)
        p.lda0 = 512; p.lda1 = 512;
        p.N0 = EMB; p.N1 = EMB; p.nx0 = 16;
        gemm_pair_kernel<64, 3, 1><<<dim3(32, TOK / BM), blk, 0, stream>>>(p, LATD);
    }

    // flash attention -> aOb
    if (split) {
        // KV-split: 1024 blocks (3/CU) -> partials, then combine
        fattn_kernel<1><<<dim3(SEQ / BQ, BATCH * HEADS, 2), dim3(512), 0, stream>>>(
            Qb, Kb, Vb, abP, aOb, Of0, Of1, Ml);
        reduce_o_kernel<<<dim3(TOK * HEADS * 16 / 256), blk, 0, stream>>>(Of0, Of1, Ml, aOb);
    } else {
        fattn_kernel<0><<<dim3(SEQ / BQ, BATCH * HEADS), dim3(512), 0, stream>>>(
            Qb, Kb, Vb, abP, aOb, nullptr, nullptr, nullptr);
    }

    // proj = aO @ Wo + bo                              (512 blocks)
    gemm_bt_kernel<0,64,3><<<dim3(EMB / 64, TOK / BM), blk, 0, stream>>>(aOb, EMB, WoT, bo, projb, EMB, EMB);

    // h = LN(x + proj) -> bf16 hb
    ln_kernel<1,0><<<dim3(TOK), blk, 0, stream>>>(x, projb, ln1w, ln1b, hb);

    // f1 = gelu(h @ W1 + b1)                           (1024 blocks)
    gemm_bt_kernel<1,128,2><<<dim3(FFND / 128, TOK / BM), blk, 0, stream>>>(hb, EMB, W1T, b1, f1, EMB, FFND);
    // f2 = f1 @ W2 + b2                                (512 blocks)
    gemm_bt_kernel<0,64,3><<<dim3(EMB / 64, TOK / BM), blk, 0, stream>>>(f1, FFND, W2T, b2, f2, FFND, EMB);

    // out = LN(h + f2) -> fp32 d_out
    ln_kernel<0,1><<<dim3(TOK), blk, 0, stream>>>(hb, f2, ln2w, ln2b, (float*)d_out);
}

// Round 14
// 360.352 us; speedup vs baseline: 1.0348x; 1.0348x over previous
//
#include <hip/hip_runtime.h>
#include <hip/hip_bf16.h>
#include <math.h>

typedef unsigned short u16;
typedef short bf16x8 __attribute__((ext_vector_type(8)));
typedef float f32x4 __attribute__((ext_vector_type(4)));

#define EMB   1024
#define HEADS 16
#define HD    64
#define LATD  256
#define FFND  4096
#define BATCH 2
#define SEQ   2048
#define TOK   (BATCH*SEQ)   // 4096

#define SCL2  0.18033688011112042f    // 0.125 * log2(e)  (folded into Wq/bq)
#define LOG2E 1.4426950408889634f

__device__ __forceinline__ float bf2f(u16 u) {
    union { unsigned int i; float f; } x; x.i = ((unsigned int)u) << 16; return x.f;
}
__device__ __forceinline__ float bfLO(unsigned int u) {
    union { unsigned int i; float f; } x; x.i = u << 16; return x.f;
}
__device__ __forceinline__ float bfHI(unsigned int u) {
    union { unsigned int i; float f; } x; x.i = u & 0xffff0000u; return x.f;
}
__device__ __forceinline__ u16 f2bf(float f) {
    union { float f; unsigned int i; } x; x.f = f;
    unsigned int i = x.i;
    unsigned int lsb = (i >> 16) & 1u;
    i += 0x7fffu + lsb;       // round-to-nearest-even
    return (u16)(i >> 16);
}
__device__ __forceinline__ void gld16(const u16* g, u16* l) {
    __builtin_amdgcn_global_load_lds(
        (const __attribute__((address_space(1))) void*)g,
        (__attribute__((address_space(3))) void*)l, 16, 0, 0);
}
__device__ __forceinline__ unsigned int cvt_pk_bf16(float a, float b) {
    unsigned int r;
    asm("v_cvt_pk_bf16_f32 %0, %1, %2" : "=v"(r) : "v"(a), "v"(b));
    return r;   // lo = bf16(a), hi = bf16(b), RNE
}
#if defined(__has_builtin)
#if __has_builtin(__builtin_amdgcn_exp2f)
#define EXP2(x) __builtin_amdgcn_exp2f(x)
#endif
#endif
#ifndef EXP2
#define EXP2(x) exp2f(x)
#endif

// ---------------------------------------------------------------- merged transpose descriptor
struct TDesc { const float* src; u16* dst; int K; int N; int ofs; float scl; };
struct TTable { TDesc d[8]; };

// ---------------------------------------------------------------- merged prep kernel:
// [0,2048)      : fp32->bf16 cvt of x
// [2048,2054)   : bias prep (concat baK|baV, bq*SCL2)
// [2054,2566)   : permute attn_bias -> abP (S^T C-frag order, x log2e, BF16 packed)
// [2566,13830)  : 8 weight transposes (fp32 -> bf16^T, optional scale)
struct PrepArgs {
    const float* x; u16* xb;
    const float* baK; const float* baV; const float* bq; float* bKV; float* bqs;
    const float* ab; u16* abP;
    TTable tt;
};

__global__ __launch_bounds__(256) void prep_all_kernel(PrepArgs pa)
{
    __shared__ u16 t[32][33];
    int blk = blockIdx.x;
    const int tid = threadIdx.x;

    if (blk < 2048) {                       // ---- cvt x -> xb (bf16), 8 elems/thread
        int i = blk * 256 + tid;            // covers TOK*EMB/8 exactly
        float4 f0 = *(const float4*)(pa.x + (size_t)i * 8);
        float4 f1 = *(const float4*)(pa.x + (size_t)i * 8 + 4);
        u16 e[8];
        e[0] = f2bf(f0.x); e[1] = f2bf(f0.y); e[2] = f2bf(f0.z); e[3] = f2bf(f0.w);
        e[4] = f2bf(f1.x); e[5] = f2bf(f1.y); e[6] = f2bf(f1.z); e[7] = f2bf(f1.w);
        *(uint4*)(pa.xb + (size_t)i * 8) = *(const uint4*)e;
        return;
    }
    blk -= 2048;
    if (blk < 6) {                          // ---- bias prep
        int i = blk * 256 + tid;            // 0..1535
        if (i < 256)      pa.bKV[i] = pa.baK[i];
        else if (i < 512) pa.bKV[i] = pa.baV[i - 256];
        else              pa.bqs[i - 512] = pa.bq[i - 512] * SCL2;
        return;
    }
    blk -= 6;
    if (blk < 512) {                        // ---- permute attn_bias (bf16 packed out)
        const int kt = blk & 31, qt = blk >> 5;
        const int lane = tid & 63, wq = tid >> 6;
        const int qq = lane >> 4, col = lane & 15;
#pragma unroll
        for (int wi = wq; wi < 8; wi += 4)
#pragma unroll
            for (int mt = 0; mt < 4; mt++) {
                float4 v = *(const float4*)(pa.ab + (size_t)(qt * 128 + wi * 16 + col) * SEQ
                                            + kt * 64 + mt * 16 + qq * 4);
                uint2 pk;
                pk.x = cvt_pk_bf16(v.x * LOG2E, v.y * LOG2E);
                pk.y = cvt_pk_bf16(v.z * LOG2E, v.w * LOG2E);
                *(uint2*)(pa.abP + (((size_t)qt * 32 + kt) * 8 + wi) * 1024 + mt * 256 + lane * 4) = pk;
            }
        return;
    }
    blk -= 512;
    {                                       // ---- weight transposes
        int tb = blk, e = 0;
#pragma unroll
        for (int i = 1; i < 8; i++) if (tb >= pa.tt.d[i].ofs) e = i;
        const float* src = pa.tt.d[e].src;
        u16* dst = pa.tt.d[e].dst;
        const int K = pa.tt.d[e].K, N = pa.tt.d[e].N;
        const float scl = pa.tt.d[e].scl;
        const int local = tb - pa.tt.d[e].ofs;
        const int nx = N >> 5;
        const int bx = (local % nx) * 32;
        const int by = (local / nx) * 32;
        const int tx = tid & 31;
        const int ty = tid >> 5;
#pragma unroll
        for (int i = 0; i < 32; i += 8)
            t[ty + i][tx] = f2bf(src[(size_t)(by + ty + i) * N + bx + tx] * scl);
        __syncthreads();
#pragma unroll
        for (int i = 0; i < 32; i += 8)
            dst[(size_t)(bx + ty + i) * K + by + tx] = t[tx][ty + i];
    }
}

// ---------------------------------------------------------------- XCD-aware block swizzle (requires nwg % 8 == 0)
__device__ __forceinline__ void xcd_swz(int& bx, int& by)
{
    const int gx = gridDim.x;
    const int nwg = gx * gridDim.y;
    const int flat = blockIdx.x + gx * blockIdx.y;
    const int swz = (flat & 7) * (nwg >> 3) + (flat >> 3);
    bx = swz % gx;
    by = swz / gx;
}

// ---------------------------------------------------------------- MFMA GEMM body (B^T, async staging, BK=64, xor-swizzled LDS)
// TRC=1 (requires BNv=64, N=1024, M spanning TOK): store C transposed as
// C[b][n][tok] (n = bx*64 + n_local, tok = m % SEQ) via LDS round-trip.
#define BM 128
#define GBK 64

template <int ACT, int BNv, int TRC>
__device__ __forceinline__ void gemm_body(
    const u16* __restrict__ A, int lda, const u16* __restrict__ WT,
    const float* __restrict__ bias, u16* __restrict__ C,
    int K, int N, int bx, int by, u16* Al, u16* Wl, u16* Tl)
{
    const int NT = BNv / 32;
    const int WN = BNv / 2;
    const int CW = BNv / 32;      // W 16B-chunks per lane (BNv*8 / 256)

    const int tid  = threadIdx.x;
    const int lane = tid & 63;
    const int w    = tid >> 6;
    const int wm = w >> 1, wn = w & 1;
    const int col = lane & 15, qq = lane >> 4;
    const size_t bm = (size_t)by * BM;
    const size_t bn = (size_t)bx * BNv;

    f32x4 acc[4][NT];
#pragma unroll
    for (int mt = 0; mt < 4; mt++)
#pragma unroll
        for (int nt = 0; nt < NT; nt++) acc[mt][nt] = (f32x4){0.f, 0.f, 0.f, 0.f};

    const u16* gA[4]; u16* lA[4];
#pragma unroll
    for (int i = 0; i < 4; i++) {
        int f = w * 256 + i * 64 + lane;
        int r = f >> 3, s = f & 7, sg = s ^ (r & 7);
        gA[i] = A + (bm + r) * (size_t)lda + sg * 8;
        lA[i] = &Al[(size_t)(w * 256 + i * 64) * 8];
    }
    const u16* gW[4]; u16* lW[4];
#pragma unroll
    for (int i = 0; i < CW; i++) {
        int f = w * (BNv * 2) + i * 64 + lane;
        int r = f >> 3, s = f & 7, sg = s ^ (r & 7);
        gW[i] = WT + (bn + r) * (size_t)K + sg * 8;
        lW[i] = &Wl[(size_t)(w * (BNv * 2) + i * 64) * 8];
    }

    for (int k0 = 0; k0 < K; k0 += GBK) {
#pragma unroll
        for (int i = 0; i < 4; i++) gld16(gA[i] + k0, lA[i]);
#pragma unroll
        for (int i = 0; i < CW; i++) gld16(gW[i] + k0, lW[i]);
        __syncthreads();

#pragma unroll
        for (int kk = 0; kk < 2; kk++) {
            bf16x8 af[4], bfr[NT];
#pragma unroll
            for (int mt = 0; mt < 4; mt++) {
                int rr = wm * 64 + mt * 16 + col;
                int sub = (kk * 4 + qq) ^ (rr & 7);
                af[mt] = *(const bf16x8*)&Al[rr * GBK + sub * 8];
            }
#pragma unroll
            for (int nt = 0; nt < NT; nt++) {
                int rn = wn * WN + nt * 16 + col;
                int sub = (kk * 4 + qq) ^ (rn & 7);
                bfr[nt] = *(const bf16x8*)&Wl[rn * GBK + sub * 8];
            }
#pragma unroll
            for (int mt = 0; mt < 4; mt++)
#pragma unroll
                for (int nt = 0; nt < NT; nt++)
                    acc[mt][nt] = __builtin_amdgcn_mfma_f32_16x16x32_bf16(
                        af[mt], bfr[nt], acc[mt][nt], 0, 0, 0);
        }
        __syncthreads();
    }

    float bv[NT];
#pragma unroll
    for (int nt = 0; nt < NT; nt++)
        bv[nt] = bias[bn + wn * WN + nt * 16 + col];

    if (TRC) {
        // transposed store: Tl[n_local][m_local], pitch 136
#pragma unroll
        for (int mt = 0; mt < 4; mt++)
#pragma unroll
            for (int nt = 0; nt < NT; nt++)
#pragma unroll
                for (int r = 0; r < 4; r++) {
                    float v = acc[mt][nt][r] + bv[nt];
                    Tl[(wn * WN + nt * 16 + col) * 136 + (wm * 64 + mt * 16 + qq * 4 + r)] = f2bf(v);
                }
        __syncthreads();
        const int b_ = (int)(bm >> 11);            // bm / SEQ (BM=128 divides SEQ)
        const size_t tokb = bm & (SEQ - 1);
        const int row = tid >> 2;                  // 0..63 (n_local)
        u16* dst = C + ((size_t)b_ * EMB + (size_t)bx * 64 + row) * SEQ + tokb;
        const u16* srcl = Tl + row * 136;
#pragma unroll
        for (int j = 0; j < 4; j++) {
            int c0 = ((tid & 3) + j * 4) * 8;
            *(uint4*)(dst + c0) = *(const uint4*)(srcl + c0);
        }
        return;
    }

#pragma unroll
    for (int mt = 0; mt < 4; mt++) {
#pragma unroll
        for (int nt = 0; nt < NT; nt++) {
#pragma unroll
            for (int r = 0; r < 4; r++) {
                float v = acc[mt][nt][r] + bv[nt];
                if (ACT == 1) v = 0.5f * v * (1.0f + erff(v * 0.70710678118654752f));
                size_t rg = bm + wm * 64 + mt * 16 + qq * 4 + r;
                C[rg * (size_t)N + bn + wn * WN + nt * 16 + col] = f2bf(v);
            }
        }
    }
}

// plain single-segment GEMM
template <int ACT, int BNv, int MINW>
__global__ __launch_bounds__(256, MINW) void gemm_bt_kernel(
    const u16* __restrict__ A, int lda, const u16* __restrict__ WT,
    const float* __restrict__ bias, u16* __restrict__ C,
    int K, int N)
{
    __shared__ __align__(16) u16 Al[BM * GBK];
    __shared__ __align__(16) u16 Wl[BNv * GBK];
    int bx, by;
    xcd_swz(bx, by);
    gemm_body<ACT, BNv, 0>(A, lda, WT, bias, C, K, N, bx, by, Al, Wl, Al);
}

// two-segment merged GEMM (same K both segments); TRV -> segment 1 stores C^T
struct GPair {
    const u16* A0; const u16* A1;
    const u16* W0; const u16* W1;
    const float* b0; const float* b1;
    u16* C0; u16* C1;
    int lda0, lda1, N0, N1, nx0;
};

template <int BNv, int MINW, int TRV>
__global__ __launch_bounds__(256, MINW) void gemm_pair_kernel(GPair p, int K)
{
    __shared__ __align__(16) u16 SH[BM * GBK + BNv * GBK];
    u16* Al = SH;
    u16* Wl = SH + BM * GBK;
    int bxs, by;
    xcd_swz(bxs, by);
    const bool s1 = bxs >= p.nx0;
    const u16* A = s1 ? p.A1 : p.A0;
    const u16* WT = s1 ? p.W1 : p.W0;
    const float* bias = s1 ? p.b1 : p.b0;
    u16* C = s1 ? p.C1 : p.C0;
    const int lda = s1 ? p.lda1 : p.lda0;
    const int N = s1 ? p.N1 : p.N0;
    const int bx = s1 ? bxs - p.nx0 : bxs;
    if (TRV && s1)
        gemm_body<0, BNv, 1>(A, lda, WT, bias, C, K, N, bx, by, Al, Wl, SH);
    else
        gemm_body<0, BNv, 0>(A, lda, WT, bias, C, K, N, bx, by, Al, Wl, SH);
}

// ---------------------------------------------------------------- flash attention (MFMA), swapped-QK^T + swapped-PV
// grid (SEQ/BQ, BATCH*HEADS); 512 thr = 8 waves; wave w owns q rows [16w, 16w+16).
// S^T = mfma(K,Q): col=q (lane&15), row=kv (qq*4+r) -> per-lane row softmax.
// PV swapped: O^T = mfma(V^T, P^T): col=q -> per-lane alpha/l, packed O stores.
// K/V LDS: LDK=64 + XOR-swizzle (chunk c -> c^(row&7)) => conflict-free b128 reads
// (PMC-verified: 1.15e7 -> 3.1e6). launch_bounds (512,4): grid is 2 blocks/CU;
// (512,6) caused scratch spills; KV-split (R13) raised WRITE 4x w/o occupancy gain.
#define BQ   128
#define BKV  64
#define NKVT (SEQ / BKV)   // 32
#define LDP  72

__global__ __launch_bounds__(512, 4) void fattn_kernel(
    const u16* __restrict__ Q, const u16* __restrict__ K,
    const u16* __restrict__ VT, const u16* __restrict__ abP,
    u16* __restrict__ O)
{
    __shared__ __align__(16) u16 Ks[2][BKV * 64];    // 2 x 8,192 B
    __shared__ __align__(16) u16 Vt[2][HD * 64];     // 2 x 8,192 B
    __shared__ __align__(16) u16 Ps[BQ * LDP];       //    18,432 B  -> total 51,200 B

    const int tid = threadIdx.x;
    const int lane = tid & 63;
    const int w = tid >> 6;                       // 0..7
    const int col = lane & 15, qq = lane >> 4;
    const int qt = blockIdx.x;                    // 0..15
    const int b = blockIdx.y >> 4, h = blockIdx.y & 15;
    const size_t tok0 = (size_t)b * SEQ + (size_t)qt * BQ;
    const int wrow = w * 16;
    const size_t kvbase = (size_t)b * SEQ * EMB + h * HD;
    const size_t vtb = ((size_t)b * EMB + h * HD) * SEQ;

    // staging indices (512 threads): 64 rows x 8 chunks of 8 elems, 1 uint4/thr each of K,V
    const int krow = tid >> 3;                    // 0..63
    const int kch  = tid & 7;                     // chunk
    const int kcol = kch * 8;                     // global k offset (linear)
    const int ksw  = (kch ^ (krow & 7)) * 8;      // swizzled LDS chunk offset

    // Q fragment: B-operand of S^T (n = q = col, k = kk*32 + qq*8); Q is pre-scaled
    bf16x8 aq[2];
#pragma unroll
    for (int kk = 0; kk < 2; kk++)
        aq[kk] = *(const bf16x8*)(Q + (tok0 + wrow + col) * EMB + h * HD + kk * 32 + qq * 8);

    float m_st = -1e30f, l_st = 0.f;
    f32x4 o_acc[4];
#pragma unroll
    for (int dt = 0; dt < 4; dt++) o_acc[dt] = (f32x4){0.f, 0.f, 0.f, 0.f};

    // swizzled read chunk offsets (row = *16+col => row&7 == col&7)
    const int c7 = col & 7;
    const int sw0 = (qq ^ c7) * 8;                // kk=0 chunk
    const int sw1 = ((4 + qq) ^ c7) * 8;          // kk=1 chunk

    uint4 kreg, vreg;
#define LOADKV(KV0) do {                                                              \
        kreg = *(const uint4*)(K + kvbase + (size_t)((KV0) + krow) * EMB + kcol);     \
        vreg = *(const uint4*)(VT + vtb + (size_t)krow * SEQ + (KV0) + kcol);         \
    } while (0)

    // prologue: stage tile 0 into buffer 0 (swizzled), then issue loads for tile 1
    LOADKV(0);
    *(uint4*)&Ks[0][krow * 64 + ksw] = kreg;
    *(uint4*)&Vt[0][krow * 64 + ksw] = vreg;
    __syncthreads();
    LOADKV(BKV);

    // attn-bias fragments for tile 0 (bf16 packed; prefetched each iteration)
    const u16* abq = abP + (size_t)qt * NKVT * 8192 + (size_t)w * 1024;
    uint2 abr[4];
#pragma unroll
    for (int mt = 0; mt < 4; mt++)
        abr[mt] = *(const uint2*)(abq + mt * 256 + lane * 4);

    for (int t = 0; t < NKVT; t++) {
        const int cur = t & 1;
        const u16* Kc = Ks[cur];

        // S^T = K·Q^T + bias (unpack bf16 bias to f32 acc; already log2-domain)
        f32x4 s2[4];
#pragma unroll
        for (int mt = 0; mt < 4; mt++) {
            s2[mt][0] = bfLO(abr[mt].x);
            s2[mt][1] = bfHI(abr[mt].x);
            s2[mt][2] = bfLO(abr[mt].y);
            s2[mt][3] = bfHI(abr[mt].y);
        }
        __builtin_amdgcn_s_setprio(1);
#pragma unroll
        for (int mt = 0; mt < 4; mt++) {
            bf16x8 ak0 = *(const bf16x8*)&Kc[(mt * 16 + col) * 64 + sw0];
            bf16x8 ak1 = *(const bf16x8*)&Kc[(mt * 16 + col) * 64 + sw1];
            s2[mt] = __builtin_amdgcn_mfma_f32_16x16x32_bf16(ak0, aq[0], s2[mt], 0, 0, 0);
            s2[mt] = __builtin_amdgcn_mfma_f32_16x16x32_bf16(ak1, aq[1], s2[mt], 0, 0, 0);
        }
        __builtin_amdgcn_s_setprio(0);

        // prefetch next tile's bias into regs
        if (t + 1 < NKVT) {
            const u16* abn = abq + (size_t)(t + 1) * 8192;
#pragma unroll
            for (int mt = 0; mt < 4; mt++)
                abr[mt] = *(const uint2*)(abn + mt * 256 + lane * 4);
        }

        // stage tile t+1 into the other buffer (swizzled; overlaps with this tile's compute)
        if (t + 1 < NKVT) {
            *(uint4*)&Ks[cur ^ 1][krow * 64 + ksw] = kreg;
            *(uint4*)&Vt[cur ^ 1][krow * 64 + ksw] = vreg;
        }
        if (t + 2 < NKVT) LOADKV((t + 2) * BKV);

        // online softmax (log2 domain), defer-max with THR=8
        float t0 = fmaxf(fmaxf(s2[0][0], s2[0][1]), fmaxf(s2[0][2], s2[0][3]));
        float t1 = fmaxf(fmaxf(s2[1][0], s2[1][1]), fmaxf(s2[1][2], s2[1][3]));
        float t2 = fmaxf(fmaxf(s2[2][0], s2[2][1]), fmaxf(s2[2][2], s2[2][3]));
        float t3 = fmaxf(fmaxf(s2[3][0], s2[3][1]), fmaxf(s2[3][2], s2[3][3]));
        float tm = fmaxf(fmaxf(t0, t1), fmaxf(t2, t3));
        tm = fmaxf(tm, __shfl_xor(tm, 16));
        tm = fmaxf(tm, __shfl_xor(tm, 32));
        if (!__all(tm <= m_st + 8.f)) {
            float mnew = fmaxf(m_st, tm);
            float alpha = EXP2(m_st - mnew);
            m_st = mnew;
            l_st *= alpha;
#pragma unroll
            for (int dt = 0; dt < 4; dt++)
#pragma unroll
                for (int r = 0; r < 4; r++) o_acc[dt][r] *= alpha;   // per-lane (col-uniform)
        }
        float rs = 0.f;
#pragma unroll
        for (int mt = 0; mt < 4; mt++)
#pragma unroll
            for (int r = 0; r < 4; r++) {
                float e = EXP2(s2[mt][r] - m_st);
                s2[mt][r] = e;
                rs += e;
            }
        rs += __shfl_xor(rs, 16);
        rs += __shfl_xor(rs, 32);
        l_st += rs;

        // P pack -> LDS: row q = wrow+col (wave-private), kv = mt*16 + qq*4..+3
#pragma unroll
        for (int mt = 0; mt < 4; mt++) {
            uint2 pp;
            pp.x = cvt_pk_bf16(s2[mt][0], s2[mt][1]);
            pp.y = cvt_pk_bf16(s2[mt][2], s2[mt][3]);
            *(uint2*)&Ps[(wrow + col) * LDP + mt * 16 + qq * 4] = pp;
        }

        // O^T += V^T @ P^T (swapped operands; same-wave LDS RAW is in-order)
        __builtin_amdgcn_s_setprio(1);
#pragma unroll
        for (int kk = 0; kk < 2; kk++) {
            bf16x8 ap = *(const bf16x8*)&Ps[(wrow + col) * LDP + kk * 32 + qq * 8];
            const int swv = ((kk * 4 + qq) ^ c7) * 8;
#pragma unroll
            for (int dt = 0; dt < 4; dt++) {
                bf16x8 bv = *(const bf16x8*)&Vt[cur][(dt * 16 + col) * 64 + swv];
                o_acc[dt] = __builtin_amdgcn_mfma_f32_16x16x32_bf16(bv, ap, o_acc[dt], 0, 0, 0);
            }
        }
        __builtin_amdgcn_s_setprio(0);
        __syncthreads();
    }
#undef LOADKV

    // epilogue: per-lane q = wrow+col; d = dt*16 + qq*4 + r -> packed 8B stores
    float lr = 1.0f / l_st;
#pragma unroll
    for (int dt = 0; dt < 4; dt++) {
        uint2 pp;
        pp.x = cvt_pk_bf16(o_acc[dt][0] * lr, o_acc[dt][1] * lr);
        pp.y = cvt_pk_bf16(o_acc[dt][2] * lr, o_acc[dt][3] * lr);
        *(uint2*)(O + (tok0 + wrow + col) * EMB + h * HD + dt * 16 + qq * 4) = pp;
    }
}

// ---------------------------------------------------------------- residual + LayerNorm (vectorized: 4 consecutive cols/thread)
template <int AF32, int OUTF32>
__global__ __launch_bounds__(256) void ln_kernel(
    const void* __restrict__ A, const u16* __restrict__ R,
    const float* __restrict__ w, const float* __restrict__ bb,
    void* __restrict__ out)
{
    __shared__ float r1[4], r2[4];
    const int tid = threadIdx.x;
    const size_t row = blockIdx.x;
    const int c0 = tid * 4;

    float v[4];
    {
        float a[4];
        if (AF32) {
            float4 av = *(const float4*)((const float*)A + row * EMB + c0);
            a[0] = av.x; a[1] = av.y; a[2] = av.z; a[3] = av.w;
        } else {
            ushort4 av = *(const ushort4*)((const u16*)A + row * EMB + c0);
            a[0] = bf2f(av.x); a[1] = bf2f(av.y); a[2] = bf2f(av.z); a[3] = bf2f(av.w);
        }
        ushort4 rv = *(const ushort4*)(R + row * EMB + c0);
        v[0] = a[0] + bf2f(rv.x); v[1] = a[1] + bf2f(rv.y);
        v[2] = a[2] + bf2f(rv.z); v[3] = a[3] + bf2f(rv.w);
    }
    float s = (v[0] + v[1]) + (v[2] + v[3]);
    float s2 = (v[0] * v[0] + v[1] * v[1]) + (v[2] * v[2] + v[3] * v[3]);

#pragma unroll
    for (int o = 32; o > 0; o >>= 1) {
        s  += __shfl_down(s, o);
        s2 += __shfl_down(s2, o);
    }
    if ((tid & 63) == 0) { r1[tid >> 6] = s; r2[tid >> 6] = s2; }
    __syncthreads();
    s  = r1[0] + r1[1] + r1[2] + r1[3];
    s2 = r2[0] + r2[1] + r2[2] + r2[3];

    float mu = s * (1.0f / EMB);
    float var = s2 * (1.0f / EMB) - mu * mu;
    float rs = rsqrtf(var + 1e-5f);

    float4 wv = *(const float4*)(w + c0);
    float4 bv = *(const float4*)(bb + c0);
    float y0 = (v[0] - mu) * rs * wv.x + bv.x;
    float y1 = (v[1] - mu) * rs * wv.y + bv.y;
    float y2 = (v[2] - mu) * rs * wv.z + bv.z;
    float y3 = (v[3] - mu) * rs * wv.w + bv.w;
    if (OUTF32) {
        *(float4*)((float*)out + row * EMB + c0) = make_float4(y0, y1, y2, y3);
    } else {
        ushort4 ov;
        ov.x = f2bf(y0); ov.y = f2bf(y1); ov.z = f2bf(y2); ov.w = f2bf(y3);
        *(ushort4*)((u16*)out + row * EMB + c0) = ov;
    }
}

// ---------------------------------------------------------------- launch
extern "C" void kernel_launch(void* const* d_in, const int* in_sizes, int n_in,
                              void* d_out, int out_size, void* d_ws, size_t ws_size,
                              hipStream_t stream)
{
    const float* x    = (const float*)d_in[0];
    const float* ab   = (const float*)d_in[1];
    const float* Wq   = (const float*)d_in[2];
    const float* bq   = (const float*)d_in[3];
    const float* WaK  = (const float*)d_in[4];
    const float* baK  = (const float*)d_in[5];
    const float* WbK  = (const float*)d_in[6];
    const float* bbK  = (const float*)d_in[7];
    const float* WaV  = (const float*)d_in[8];
    const float* baV  = (const float*)d_in[9];
    const float* WbV  = (const float*)d_in[10];
    const float* bbV  = (const float*)d_in[11];
    const float* Wo   = (const float*)d_in[12];
    const float* bo   = (const float*)d_in[13];
    const float* W1   = (const float*)d_in[14];
    const float* b1   = (const float*)d_in[15];
    const float* W2   = (const float*)d_in[16];
    const float* b2   = (const float*)d_in[17];
    const float* ln1w = (const float*)d_in[18];
    const float* ln1b = (const float*)d_in[19];
    const float* ln2w = (const float*)d_in[20];
    const float* ln2b = (const float*)d_in[21];

    u16* w = (u16*)d_ws;
    size_t o = 0;
    u16* WqT  = w + o; o += (size_t)EMB * EMB;
    u16* WaKT = w + o; o += (size_t)EMB * LATD;    // WaKT+WaVT contiguous = combined WT
    u16* WaVT = w + o; o += (size_t)EMB * LATD;
    u16* WbKT = w + o; o += (size_t)LATD * EMB;
    u16* WbVT = w + o; o += (size_t)LATD * EMB;
    u16* WoT  = w + o; o += (size_t)EMB * EMB;
    u16* W1T  = w + o; o += (size_t)EMB * FFND;
    u16* W2T  = w + o; o += (size_t)FFND * EMB;
    u16* Qb   = w + o; o += (size_t)TOK * EMB;
    u16* Kb   = w + o; o += (size_t)TOK * EMB;
    u16* Vb   = w + o; o += (size_t)TOK * EMB;     // holds VbT: [b][h*64+d][tok]
    u16* aOb  = w + o; o += (size_t)TOK * EMB;
    u16* projb= w + o; o += (size_t)TOK * EMB;
    u16* hb   = w + o; o += (size_t)TOK * EMB;
    u16* xb   = w + o; o += (size_t)TOK * EMB;     // bf16 x (own slot)
    float* bKV = (float*)(w + o); o += 1024;       // 512 fp32 concat bias
    float* bqs = (float*)(w + o); o += 2048;       // 1024 fp32 scaled bq
    // overlays (non-overlapping lifetimes):
    u16* abP = projb;                         // 8.4 MB bf16 = projb slot exactly; dead after fattn
    u16* KVa = aOb;                           // [TOK][512]; dead before fattn writes aOb
    u16* f1  = Qb;                            // spans Qb..aOb = TOK*FFND
    u16* f2  = projb;                         // abP/proj dead after ln1

    dim3 blk(256);

    // merged prep: cvt | bias | permute_ab(bf16) | 8 transposes (2048+6+512+11264 = 13830 blocks)
    PrepArgs pa;
    pa.x = x; pa.xb = xb;
    pa.baK = baK; pa.baV = baV; pa.bq = bq; pa.bKV = bKV; pa.bqs = bqs;
    pa.ab = ab; pa.abP = abP;
    pa.tt.d[0] = {Wq,  WqT,  EMB,  EMB,  0,    SCL2};   // Q pre-scaled by 0.125*log2e
    pa.tt.d[1] = {WaK, WaKT, EMB,  LATD, 1024, 1.0f};
    pa.tt.d[2] = {WaV, WaVT, EMB,  LATD, 1280, 1.0f};
    pa.tt.d[3] = {WbK, WbKT, LATD, EMB,  1536, 1.0f};
    pa.tt.d[4] = {WbV, WbVT, LATD, EMB,  1792, 1.0f};
    pa.tt.d[5] = {Wo,  WoT,  EMB,  EMB,  2048, 1.0f};
    pa.tt.d[6] = {W1,  W1T,  EMB,  FFND, 3072, 1.0f};
    pa.tt.d[7] = {W2,  W2T,  FFND, EMB,  7168, 1.0f};
    prep_all_kernel<<<dim3(13830), blk, 0, stream>>>(pa);

    // merged: Q = x@(Wq*s)+bq*s (16 n-blocks) | KVa = x@[WaK|WaV]+bKV (8 n-blocks); K=1024
    {
        GPair p;
        p.A0 = xb;  p.A1 = xb;
        p.W0 = WqT; p.W1 = WaKT;
        p.b0 = bqs; p.b1 = bKV;
        p.C0 = Qb;  p.C1 = KVa;
        p.lda0 = EMB; p.lda1 = EMB;
        p.N0 = EMB; p.N1 = 512; p.nx0 = 16;
        gemm_pair_kernel<64, 3, 0><<<dim3(24, TOK / BM), blk, 0, stream>>>(p, EMB);
    }
    // merged: K = Ka@WbK+bbK | V^T = (Va@WbV+bbV)^T; K=256, both N=1024 (16+16 n-blocks)
    {
        GPair p;
        p.A0 = KVa;  p.A1 = KVa + LATD;
        p.W0 = WbKT; p.W1 = WbVT;
        p.b0 = bbK;  p.b1 = bbV;
        p.C0 = Kb;   p.C1 = Vb;          // Vb stored transposed (VbT)
        p.lda0 = 512; p.lda1 = 512;
        p.N0 = EMB; p.N1 = EMB; p.nx0 = 16;
        gemm_pair_kernel<64, 3, 1><<<dim3(32, TOK / BM), blk, 0, stream>>>(p, LATD);
    }

    // flash attention -> aOb                           (512 blocks x 512 thr)
    fattn_kernel<<<dim3(SEQ / BQ, BATCH * HEADS), dim3(512), 0, stream>>>(Qb, Kb, Vb, abP, aOb);

    // proj = aO @ Wo + bo                              (512 blocks)
    gemm_bt_kernel<0,64,3><<<dim3(EMB / 64, TOK / BM), blk, 0, stream>>>(aOb, EMB, WoT, bo, projb, EMB, EMB);

    // h = LN(x + proj) -> bf16 hb
    ln_kernel<1,0><<<dim3(TOK), blk, 0, stream>>>(x, projb, ln1w, ln1b, hb);

    // f1 = gelu(h @ W1 + b1)                           (1024 blocks)
    gemm_bt_kernel<1,128,2><<<dim3(FFND / 128, TOK / BM), blk, 0, stream>>>(hb, EMB, W1T, b1, f1, EMB, FFND);
    // f2 = f1 @ W2 + b2                                (512 blocks)
    gemm_bt_kernel<0,64,3><<<dim3(EMB / 64, TOK / BM), blk, 0, stream>>>(f1, FFND, W2T, b2, f2, FFND, EMB);

    // out = LN(h + f2) -> fp32 d_out
    ln_kernel<0,1><<<dim3(TOK), blk, 0, stream>>>(hb, f2, ln2w, ln2b, (float*)d_out);
}